// Round 3
// baseline (377.808 us; speedup 1.0000x reference)
//
#include <hip/hip_runtime.h>
#include <hip/hip_bf16.h>

typedef unsigned short ushort_t;
typedef unsigned int   uint_t;

#define STR 516   // padded row stride (floats): 516*4B = 2064B, 16B-aligned, +4 bank skew per row

__device__ __forceinline__ float4 fma4(float4 a, float s, float4 w){
  a.x += s*w.x; a.y += s*w.y; a.z += s*w.z; a.w += s*w.w; return a;
}
__device__ __forceinline__ float4 relu4(float4 a){
  return make_float4(fmaxf(a.x,0.f),fmaxf(a.y,0.f),fmaxf(a.z,0.f),fmaxf(a.w,0.f));
}
__device__ __forceinline__ float comp4(float4 v, int k){
  return k==0? v.x : k==1? v.y : k==2? v.z : v.w;
}

// One GATv2 layer: x (32 x D, fp32, LDS rows stride STR) -> x = relu(gatv2(x)+bias) in place.
// gl -> s_gl, gr computed then overwrites s_x, logits -> s_lg, softmax in place, aggregate -> s_x.
template<int D>
__device__ __forceinline__ void gat_layer(
    const float* __restrict__ wl, const float* __restrict__ wr,
    const float* __restrict__ att, const float* __restrict__ bias,
    float* s_x, float* s_gl, float* s_lg, float* s_att,
    const unsigned* s_adj, int t)
{
  const int w = t>>6, lane = t&63;

  // stage att (4x128) into LDS; consumed after the post-GEMM barrier
  for (int e=t; e<512; e+=256) s_att[e] = att[e];
  // per-thread bias for aggregation columns (2t, 2t+1)
  const float2 bias2 = *(const float2*)(bias + 2*t);

  // ---- projections: gl = x@wl -> s_gl ; gr = x@wr -> s_x (in-place) ----
  // wave w: rows r0..r0+15, cols c0..c0+3 (2-way row split x 2-way col split)
  const int r0 = (w&1)*16;
  const int c0 = (w>>1)*256 + lane*4;
  float4 agl[16], agr[16];
  #pragma unroll
  for (int r=0;r<16;r++){ agl[r]=make_float4(0.f,0.f,0.f,0.f); agr[r]=make_float4(0.f,0.f,0.f,0.f); }
  for (int k=0;k<D;k+=4){
    float4 xv[16];
    #pragma unroll
    for (int r=0;r<16;r++) xv[r] = *(const float4*)&s_x[(r0+r)*STR + k];
    #pragma unroll
    for (int kk=0;kk<4;kk++){
      const float4 wlv = *(const float4*)(wl + (k+kk)*512 + c0);
      const float4 wrv = *(const float4*)(wr + (k+kk)*512 + c0);
      #pragma unroll
      for (int r=0;r<16;r++){
        const float xs = comp4(xv[r], kk);
        agl[r] = fma4(agl[r], xs, wlv);
        agr[r] = fma4(agr[r], xs, wrv);
      }
    }
  }
  __syncthreads();          // all waves done reading x
  #pragma unroll
  for (int r=0;r<16;r++){
    *(float4*)&s_gl[(r0+r)*STR + c0] = agl[r];
    *(float4*)&s_x [(r0+r)*STR + c0] = agr[r];   // gr overwrites x
  }
  __syncthreads();

  // ---- logits[i][j][h] = sum_c lrelu(gr[i][c]+gl[j][c]) * att[h][c] ----
  {
    const int i = t>>3, jb = t&7;
    float acc[4][4];
    #pragma unroll
    for (int m=0;m<4;m++)
      #pragma unroll
      for (int h=0;h<4;h++) acc[m][h]=0.f;
    #pragma unroll
    for (int h=0;h<4;h++){
      for (int cc=0; cc<128; cc+=4){
        const int c = h*128+cc;
        const float4 g = *(const float4*)&s_x[i*STR+c];
        const float4 a = *(const float4*)&s_att[c];
        #pragma unroll
        for (int m=0;m<4;m++){
          const float4 gj = *(const float4*)&s_gl[(jb+8*m)*STR + c];
          float ex = g.x+gj.x; ex = fmaxf(ex, 0.2f*ex);
          float ey = g.y+gj.y; ey = fmaxf(ey, 0.2f*ey);
          float ez = g.z+gj.z; ez = fmaxf(ez, 0.2f*ez);
          float ew = g.w+gj.w; ew = fmaxf(ew, 0.2f*ew);
          acc[m][h] += ex*a.x + ey*a.y + ez*a.z + ew*a.w;
        }
      }
    }
    #pragma unroll
    for (int m=0;m<4;m++)
      #pragma unroll
      for (int h=0;h<4;h++)
        s_lg[i*128 + h*32 + jb + 8*m] = acc[m][h];
  }
  __syncthreads();

  // ---- masked softmax over j (in-place -> alpha), 2 rows i per round ----
  for (int rnd=0; rnd<16; rnd++){
    const int i = 2*rnd + (t>>7);
    const int h = (t>>5)&3, j = t&31;
    const int idx = i*128 + h*32 + j;
    const float lg = s_lg[idx];
    const bool ok = (s_adj[i]>>j)&1u;
    float v = ok ? lg : -3.0e38f;
    #pragma unroll
    for (int d_=16; d_; d_>>=1) v = fmaxf(v, __shfl_xor(v, d_, 32));
    const float e = ok ? __expf(lg - v) : 0.f;
    float s = e;
    #pragma unroll
    for (int d_=16; d_; d_>>=1) s += __shfl_xor(s, d_, 32);
    s_lg[idx] = e / s;
  }
  __syncthreads();

  // ---- aggregate: x = relu(alpha @ gl + bias) -> s_x (4 rows i at a time) ----
  {
    const int cA = 2*t;        // contiguous col pair
    const int h  = t>>6;       // single head per wave (cA>>7 == t>>6)
    for (int ib=0; ib<8; ib++){
      float2 acc[4];
      #pragma unroll
      for (int q=0;q<4;q++) acc[q]=make_float2(0.f,0.f);
      for (int jc=0; jc<32; jc+=4){
        float4 al[4];
        #pragma unroll
        for (int q=0;q<4;q++) al[q] = *(const float4*)&s_lg[(ib*4+q)*128 + h*32 + jc];
        #pragma unroll
        for (int m=0;m<4;m++){
          const float2 g = *(const float2*)&s_gl[(jc+m)*STR + cA];
          #pragma unroll
          for (int q=0;q<4;q++){
            const float av = comp4(al[q], m);
            acc[q].x += av*g.x;
            acc[q].y += av*g.y;
          }
        }
      }
      #pragma unroll
      for (int q=0;q<4;q++){
        const float ox = fmaxf(acc[q].x + bias2.x, 0.f);
        const float oy = fmaxf(acc[q].y + bias2.y, 0.f);
        *(float2*)&s_x[(ib*4+q)*STR + cA] = make_float2(ox,oy);
      }
    }
  }
  __syncthreads();
}

__global__ __launch_bounds__(256, 1) void ldgn_kernel(
    const float* __restrict__ obs,
    const float* __restrict__ enc_w1, const float* __restrict__ enc_b1,
    const float* __restrict__ enc_w2, const float* __restrict__ enc_b2,
    const float* __restrict__ wl1, const float* __restrict__ wr1,
    const float* __restrict__ att1, const float* __restrict__ bias1,
    const float* __restrict__ wl2, const float* __restrict__ wr2,
    const float* __restrict__ att2, const float* __restrict__ bias2_,
    const float* __restrict__ q_w1, const float* __restrict__ q_b1,
    const float* __restrict__ q_w2, const float* __restrict__ q_b2,
    const float* __restrict__ v_w1, const float* __restrict__ v_b1,
    const float* __restrict__ v_w2, const float* __restrict__ v_b2,
    float* __restrict__ out)
{
  __shared__ __align__(16) float s_x [32*STR];   // 66048 B
  __shared__ __align__(16) float s_gl[32*STR];   // 66048 B
  __shared__ __align__(16) float s_lg[32*4*32];  // 16384 B logits/alpha
  __shared__ __align__(16) float s_att[512];
  __shared__ __align__(16) float s_xcat[1152];
  __shared__ __align__(16) float s_head[512];
  __shared__ __align__(16) float s_pos[64];
  __shared__ __align__(16) float s_feats[512];
  __shared__ unsigned s_adj[32];
  __shared__ float s_red[40];
  __shared__ int s_ai;
  // total ~159.8 KB < 160 KiB gfx950 LDS; 1 block/CU by design

  const int t = threadIdx.x;
  const int b = blockIdx.x;
  const float* ob = obs + b*577;

  // ---- parse obs: pos, feats, agent idx ----
  if (t < 64) s_pos[t] = ob[(t>>1)*18 + (t&1)];
  for (int e=t; e<512; e+=256){ const int i=e>>4, f=e&15; s_feats[e] = ob[i*18+2+f]; }
  if (t==0){
    float a = ob[576];
    a = fminf(fmaxf(a, 0.f), 31.f);
    s_ai = (int)a;
  }
  __syncthreads();

  // ---- adjacency bitmask (exact fp32 rounding: no fma contraction, match np) ----
  if (t < 32){
    const float px = s_pos[2*t], py = s_pos[2*t+1];
    const float R2 = 0.09f;
    unsigned m = 0u;
    for (int j=0;j<32;j++){
      const float dx = __fsub_rn(px, s_pos[2*j]), dy = __fsub_rn(py, s_pos[2*j+1]);
      const float d2 = __fadd_rn(__fmul_rn(dx,dx), __fmul_rn(dy,dy));
      if (d2 < R2 || j==t) m |= (1u<<j);
    }
    s_adj[t] = m;
  }

  // ---- encoder 1: h = relu(feats @ enc_w1 + b1) -> s_gl (32x128) ----
  {
    const int i = t>>3, c0 = (t&7)*16;
    float4 a0 = *(const float4*)(enc_b1+c0);
    float4 a1 = *(const float4*)(enc_b1+c0+4);
    float4 a2 = *(const float4*)(enc_b1+c0+8);
    float4 a3 = *(const float4*)(enc_b1+c0+12);
    for (int f=0; f<16; f++){
      const float xs = s_feats[i*16+f];
      const float* p = enc_w1 + f*128 + c0;
      a0 = fma4(a0, xs, *(const float4*)(p));
      a1 = fma4(a1, xs, *(const float4*)(p+4));
      a2 = fma4(a2, xs, *(const float4*)(p+8));
      a3 = fma4(a3, xs, *(const float4*)(p+12));
    }
    *(float4*)&s_gl[i*STR+c0]    = relu4(a0);
    *(float4*)&s_gl[i*STR+c0+4]  = relu4(a1);
    *(float4*)&s_gl[i*STR+c0+8]  = relu4(a2);
    *(float4*)&s_gl[i*STR+c0+12] = relu4(a3);
  }
  __syncthreads();

  // ---- encoder 2: x = relu(h @ enc_w2 + b2) -> s_x (32x128) ----
  {
    const int i = t>>3, c0 = (t&7)*16;
    float4 a0 = *(const float4*)(enc_b2+c0);
    float4 a1 = *(const float4*)(enc_b2+c0+4);
    float4 a2 = *(const float4*)(enc_b2+c0+8);
    float4 a3 = *(const float4*)(enc_b2+c0+12);
    for (int k=0;k<128;k+=4){
      const float4 hv = *(const float4*)&s_gl[i*STR+k];
      #pragma unroll
      for (int kk=0;kk<4;kk++){
        const float* p = enc_w2 + (k+kk)*128 + c0;
        const float xs = comp4(hv,kk);
        a0 = fma4(a0, xs, *(const float4*)(p));
        a1 = fma4(a1, xs, *(const float4*)(p+4));
        a2 = fma4(a2, xs, *(const float4*)(p+8));
        a3 = fma4(a3, xs, *(const float4*)(p+12));
      }
    }
    *(float4*)&s_x[i*STR+c0]    = relu4(a0);
    *(float4*)&s_x[i*STR+c0+4]  = relu4(a1);
    *(float4*)&s_x[i*STR+c0+8]  = relu4(a2);
    *(float4*)&s_x[i*STR+c0+12] = relu4(a3);
  }
  __syncthreads();

  // x1 = x[aidx]
  if (t < 128) s_xcat[t] = s_x[s_ai*STR + t];

  gat_layer<128>(wl1, wr1, att1, bias1, s_x, s_gl, s_lg, s_att, s_adj, t);

  // x2 = x[aidx]
  for (int e=t; e<512; e+=256) s_xcat[128+e] = s_x[s_ai*STR+e];

  gat_layer<512>(wl2, wr2, att2, bias2_, s_x, s_gl, s_lg, s_att, s_adj, t);

  // x3 = x[aidx]
  for (int e=t; e<512; e+=256) s_xcat[640+e] = s_x[s_ai*STR+e];
  __syncthreads();

  // ---- dueling heads layer 1: hq = relu(xcat@q_w1+q_b1), hv = relu(xcat@v_w1+v_b1) ----
  {
    const float* w1p; const float* b1p; int cbase, off;
    if (t < 128){ w1p = q_w1; b1p = q_b1; cbase = 2*t;        off = 0;   }
    else        { w1p = v_w1; b1p = v_b1; cbase = 2*(t-128);  off = 256; }
    float2 acc = make_float2(0.f,0.f);
    for (int k=0;k<1152;k+=4){
      const float4 xv = *(const float4*)&s_xcat[k];
      #pragma unroll
      for (int kk=0;kk<4;kk++){
        const float2 wv = *(const float2*)(w1p + (k+kk)*256 + cbase);
        const float xs = comp4(xv,kk);
        acc.x += xs*wv.x;
        acc.y += xs*wv.y;
      }
    }
    const float2 bv = *(const float2*)(b1p + cbase);
    s_head[off+cbase]   = fmaxf(acc.x + bv.x, 0.f);
    s_head[off+cbase+1] = fmaxf(acc.y + bv.y, 0.f);
  }
  __syncthreads();

  // ---- final: q = hq@q_w2+q_b2 (5), v = hv@v_w2+v_b2 (1), out = q - mean(q) + v ----
  {
    const float hq = s_head[t];
    const float hv = s_head[256+t];
    float p0 = hq*q_w2[t*5+0];
    float p1 = hq*q_w2[t*5+1];
    float p2 = hq*q_w2[t*5+2];
    float p3 = hq*q_w2[t*5+3];
    float p4 = hq*q_w2[t*5+4];
    float p5 = hv*v_w2[t];
    #pragma unroll
    for (int d_=32; d_; d_>>=1){
      p0 += __shfl_xor(p0, d_, 64);
      p1 += __shfl_xor(p1, d_, 64);
      p2 += __shfl_xor(p2, d_, 64);
      p3 += __shfl_xor(p3, d_, 64);
      p4 += __shfl_xor(p4, d_, 64);
      p5 += __shfl_xor(p5, d_, 64);
    }
    const int w = t>>6, lane = t&63;
    if (lane==0){
      s_red[w*8+0]=p0; s_red[w*8+1]=p1; s_red[w*8+2]=p2;
      s_red[w*8+3]=p3; s_red[w*8+4]=p4; s_red[w*8+5]=p5;
    }
  }
  __syncthreads();
  if (t < 5){
    const float q = s_red[t] + s_red[8+t] + s_red[16+t] + s_red[24+t] + q_b2[t];
    s_red[32+t] = q;
  }
  __syncthreads();
  if (t < 5){
    const float vs = s_red[5] + s_red[13] + s_red[21] + s_red[29] + v_b2[0];
    const float mean = (s_red[32]+s_red[33]+s_red[34]+s_red[35]+s_red[36]) / 5.0f;
    out[b*5+t] = s_red[32+t] - mean + vs;
  }
}

extern "C" void kernel_launch(void* const* d_in, const int* in_sizes, int n_in,
                              void* d_out, int out_size, void* d_ws, size_t ws_size,
                              hipStream_t stream) {
  (void)n_in; (void)out_size; (void)d_ws; (void)ws_size;
  const float* obs    = (const float*)d_in[0];
  const float* enc_w1 = (const float*)d_in[1];
  const float* enc_b1 = (const float*)d_in[2];
  const float* enc_w2 = (const float*)d_in[3];
  const float* enc_b2 = (const float*)d_in[4];
  const float* wl1    = (const float*)d_in[5];
  const float* wr1    = (const float*)d_in[6];
  const float* att1   = (const float*)d_in[7];
  const float* bias1  = (const float*)d_in[8];
  const float* wl2    = (const float*)d_in[9];
  const float* wr2    = (const float*)d_in[10];
  const float* att2   = (const float*)d_in[11];
  const float* bias2  = (const float*)d_in[12];
  const float* q_w1   = (const float*)d_in[13];
  const float* q_b1   = (const float*)d_in[14];
  const float* q_w2   = (const float*)d_in[15];
  const float* q_b2   = (const float*)d_in[16];
  const float* v_w1   = (const float*)d_in[17];
  const float* v_b1   = (const float*)d_in[18];
  const float* v_w2   = (const float*)d_in[19];
  const float* v_b2   = (const float*)d_in[20];

  const int bs = in_sizes[0] / 577;   // 128
  ldgn_kernel<<<bs, 256, 0, stream>>>(obs, enc_w1, enc_b1, enc_w2, enc_b2,
                                      wl1, wr1, att1, bias1,
                                      wl2, wr2, att2, bias2,
                                      q_w1, q_b1, q_w2, q_b2,
                                      v_w1, v_b1, v_w2, v_b2,
                                      (float*)d_out);
}

// Round 4
// 290.106 us; speedup vs baseline: 1.3023x; 1.3023x over previous
//
#include <hip/hip_runtime.h>
#include <hip/hip_bf16.h>

typedef unsigned int uint_t;

__device__ __forceinline__ float4 fma4(float4 a, float s, float4 w){
  a.x += s*w.x; a.y += s*w.y; a.z += s*w.z; a.w += s*w.w; return a;
}
__device__ __forceinline__ float4 relu4(float4 a){
  return make_float4(fmaxf(a.x,0.f),fmaxf(a.y,0.f),fmaxf(a.z,0.f),fmaxf(a.w,0.f));
}
__device__ __forceinline__ float comp4(float4 v, int k){
  return k==0? v.x : k==1? v.y : k==2? v.z : v.w;
}

// =============== K1: encoder + adjacency + x1 tap ===============
__global__ __launch_bounds__(256) void enc_kernel(
    const float* __restrict__ obs,
    const float* __restrict__ enc_w1, const float* __restrict__ enc_b1,
    const float* __restrict__ enc_w2, const float* __restrict__ enc_b2,
    float* __restrict__ xg,      // [4096][128]
    float* __restrict__ xcat,    // [128][1152]
    unsigned* __restrict__ adjw, int* __restrict__ aiw)
{
  __shared__ float s_pos[64];
  __shared__ float s_feats[512];
  __shared__ __align__(16) float s_h[32*132];
  __shared__ int s_ai;
  const int t = threadIdx.x, s = blockIdx.x;
  const float* ob = obs + s*577;

  if (t < 64) s_pos[t] = ob[(t>>1)*18 + (t&1)];
  for (int e=t; e<512; e+=256){ const int i=e>>4, f=e&15; s_feats[e] = ob[i*18+2+f]; }
  if (t==0){
    float a = ob[576];
    a = fminf(fmaxf(a, 0.f), 31.f);
    const int ai = (int)a;
    s_ai = ai; aiw[s] = ai;
  }
  __syncthreads();

  if (t < 32){
    const float px = s_pos[2*t], py = s_pos[2*t+1];
    const float R2 = 0.09f;   // fp32(0.09); np compares f32 d2 < 0.09f64  <=>  d2 <= R2
    unsigned m = 0u;
    for (int j=0;j<32;j++){
      const float dx = __fsub_rn(px, s_pos[2*j]), dy = __fsub_rn(py, s_pos[2*j+1]);
      const float d2 = __fadd_rn(__fmul_rn(dx,dx), __fmul_rn(dy,dy));
      if (d2 <= R2 || j==t) m |= (1u<<j);
    }
    adjw[s*32+t] = m;
  }

  // enc1: h = relu(feats @ enc_w1 + b1) -> s_h
  {
    const int i = t>>3, c0 = (t&7)*16;
    float4 a0 = *(const float4*)(enc_b1+c0);
    float4 a1 = *(const float4*)(enc_b1+c0+4);
    float4 a2 = *(const float4*)(enc_b1+c0+8);
    float4 a3 = *(const float4*)(enc_b1+c0+12);
    for (int f=0; f<16; f++){
      const float xs = s_feats[i*16+f];
      const float* p = enc_w1 + f*128 + c0;
      a0 = fma4(a0, xs, *(const float4*)(p));
      a1 = fma4(a1, xs, *(const float4*)(p+4));
      a2 = fma4(a2, xs, *(const float4*)(p+8));
      a3 = fma4(a3, xs, *(const float4*)(p+12));
    }
    *(float4*)&s_h[i*132+c0]    = relu4(a0);
    *(float4*)&s_h[i*132+c0+4]  = relu4(a1);
    *(float4*)&s_h[i*132+c0+8]  = relu4(a2);
    *(float4*)&s_h[i*132+c0+12] = relu4(a3);
  }
  __syncthreads();

  // enc2: x = relu(h @ enc_w2 + b2) -> global xg + tap
  {
    const int i = t>>3, c0 = (t&7)*16;
    float4 a0 = *(const float4*)(enc_b2+c0);
    float4 a1 = *(const float4*)(enc_b2+c0+4);
    float4 a2 = *(const float4*)(enc_b2+c0+8);
    float4 a3 = *(const float4*)(enc_b2+c0+12);
    for (int k=0;k<128;k+=4){
      const float4 hv = *(const float4*)&s_h[i*132+k];
      #pragma unroll
      for (int kk=0;kk<4;kk++){
        const float* p = enc_w2 + (k+kk)*128 + c0;
        const float xs = comp4(hv,kk);
        a0 = fma4(a0, xs, *(const float4*)(p));
        a1 = fma4(a1, xs, *(const float4*)(p+4));
        a2 = fma4(a2, xs, *(const float4*)(p+8));
        a3 = fma4(a3, xs, *(const float4*)(p+12));
      }
    }
    a0 = relu4(a0); a1 = relu4(a1); a2 = relu4(a2); a3 = relu4(a3);
    float* xp = xg + ((size_t)s*32 + i)*128;
    *(float4*)&xp[c0]    = a0;
    *(float4*)&xp[c0+4]  = a1;
    *(float4*)&xp[c0+8]  = a2;
    *(float4*)&xp[c0+12] = a3;
    if (i == s_ai){
      float* xc = xcat + (size_t)s*1152;
      *(float4*)&xc[c0]    = a0;
      *(float4*)&xc[c0+4]  = a1;
      *(float4*)&xc[c0+8]  = a2;
      *(float4*)&xc[c0+12] = a3;
    }
  }
}

// =============== K2/K4: tiled GEMM  C[4096xN] = A[4096xK] @ B[Kx512] ===============
// 64 rows x 128 cols per block, 256 threads, 8x4 per thread, BK=32.
// ct < ctsplit -> (B0,C0) else (B1,C1) with col base recomputed.
template<int KDIM>
__global__ __launch_bounds__(256) void gemm_kernel(
    const float* __restrict__ A,
    const float* __restrict__ B0, const float* __restrict__ B1,
    float* __restrict__ C0, float* __restrict__ C1,
    int nct, int ctsplit)
{
  __shared__ __align__(16) float As[64*36];
  __shared__ __align__(16) float Bs[32*132];
  const int t = threadIdx.x;
  const int bid = blockIdx.x;
  const int rt = bid / nct, ct = bid % nct;
  const float* B; float* C; int cb;
  if (ct < ctsplit){ B = B0; C = C0; cb = ct*128; }
  else             { B = B1; C = C1; cb = (ct-ctsplit)*128; }
  const int rbase = rt*64;
  const int r0 = (t>>5)*8;       // 0..56 step 8
  const int c0 = (t&31)*4;       // 0..124

  float4 acc[8];
  #pragma unroll
  for (int r=0;r<8;r++) acc[r] = make_float4(0.f,0.f,0.f,0.f);

  for (int k0 = 0; k0 < KDIM; k0 += 32){
    float4 a_st[2], b_st[4];
    #pragma unroll
    for (int i=0;i<2;i++){
      const int e = t + i*256, row = e>>3, kq = e&7;
      a_st[i] = *(const float4*)&A[(size_t)(rbase+row)*KDIM + k0 + kq*4];
    }
    #pragma unroll
    for (int i=0;i<4;i++){
      const int e = t + i*256, kk = e>>5, c4 = e&31;
      b_st[i] = *(const float4*)&B[(size_t)(k0+kk)*512 + cb + c4*4];
    }
    __syncthreads();
    #pragma unroll
    for (int i=0;i<2;i++){
      const int e = t + i*256, row = e>>3, kq = e&7;
      *(float4*)&As[row*36 + kq*4] = a_st[i];
    }
    #pragma unroll
    for (int i=0;i<4;i++){
      const int e = t + i*256, kk = e>>5, c4 = e&31;
      *(float4*)&Bs[kk*132 + c4*4] = b_st[i];
    }
    __syncthreads();
    #pragma unroll
    for (int kk4=0; kk4<8; kk4++){
      float4 bv[4];
      #pragma unroll
      for (int kk=0;kk<4;kk++) bv[kk] = *(const float4*)&Bs[(kk4*4+kk)*132 + c0];
      #pragma unroll
      for (int r=0;r<8;r++){
        const float4 av = *(const float4*)&As[(r0+r)*36 + kk4*4];
        acc[r] = fma4(acc[r], av.x, bv[0]);
        acc[r] = fma4(acc[r], av.y, bv[1]);
        acc[r] = fma4(acc[r], av.z, bv[2]);
        acc[r] = fma4(acc[r], av.w, bv[3]);
      }
    }
  }
  #pragma unroll
  for (int r=0;r<8;r++){
    *(float4*)&C[(size_t)(rbase + r0 + r)*512 + cb + c0] = acc[r];
  }
}

// =============== K3: GAT layer-1 attention, one block per (sample, head) ===============
__global__ __launch_bounds__(256) void attn1_kernel(
    const float* __restrict__ gl, const float* __restrict__ gr, // [4096][512]
    const float* __restrict__ att, const float* __restrict__ bias, // [4][128], [512]
    const unsigned* __restrict__ adjw, const int* __restrict__ aiw,
    float* __restrict__ x2,   // [4096][512] (aliases gr buffer; safe: slice h only touched by block (s,h))
    float* __restrict__ xcat) // [128][1152]
{
  __shared__ __align__(16) float s_gl[32*132];
  __shared__ __align__(16) float s_gr[32*132];
  __shared__ __align__(16) float s_att[128];
  __shared__ __align__(16) float s_b[128];
  __shared__ float s_lg[32*33];
  __shared__ unsigned s_adj[32];
  const int t = threadIdx.x;
  const int s = blockIdx.x >> 2, h = blockIdx.x & 3;
  const float* glp = gl + (size_t)s*32*512 + h*128;
  const float* grp = gr + (size_t)s*32*512 + h*128;

  {
    const int i = t>>3, c0 = (t&7)*16;
    #pragma unroll
    for (int q=0;q<4;q++){
      *(float4*)&s_gl[i*132 + c0 + q*4] = *(const float4*)&glp[(size_t)i*512 + c0 + q*4];
      *(float4*)&s_gr[i*132 + c0 + q*4] = *(const float4*)&grp[(size_t)i*512 + c0 + q*4];
    }
  }
  if (t < 128){ s_att[t] = att[h*128 + t]; s_b[t] = bias[h*128 + t]; }
  if (t >= 224) s_adj[t-224] = adjw[s*32 + (t-224)];
  const int ai = aiw[s];
  __syncthreads();

  // logits[i][j] = att_h . lrelu(gr[i] + gl[j])
  {
    const int i = t>>3, jb = t&7;
    float acc[4] = {0.f,0.f,0.f,0.f};
    for (int c=0;c<128;c+=4){
      const float4 g = *(const float4*)&s_gr[i*132+c];
      const float4 a = *(const float4*)&s_att[c];
      #pragma unroll
      for (int m=0;m<4;m++){
        const float4 gj = *(const float4*)&s_gl[(jb+8*m)*132 + c];
        float ex = g.x+gj.x; ex = fmaxf(ex, 0.2f*ex);
        float ey = g.y+gj.y; ey = fmaxf(ey, 0.2f*ey);
        float ez = g.z+gj.z; ez = fmaxf(ez, 0.2f*ez);
        float ew = g.w+gj.w; ew = fmaxf(ew, 0.2f*ew);
        acc[m] += ex*a.x + ey*a.y + ez*a.z + ew*a.w;
      }
    }
    #pragma unroll
    for (int m=0;m<4;m++) s_lg[i*33 + jb + 8*m] = acc[m];
  }
  __syncthreads();

  // masked softmax over j (rows i: 4 rounds of 8)
  for (int rnd=0; rnd<4; rnd++){
    const int i = rnd*8 + (t>>5), j = t&31;
    const float lg = s_lg[i*33+j];
    const bool ok = (s_adj[i]>>j)&1u;
    float v = ok ? lg : -3.0e38f;
    #pragma unroll
    for (int d_=16; d_; d_>>=1) v = fmaxf(v, __shfl_xor(v, d_, 32));
    const float e = ok ? __expf(lg - v) : 0.f;
    float sum = e;
    #pragma unroll
    for (int d_=16; d_; d_>>=1) sum += __shfl_xor(sum, d_, 32);
    s_lg[i*33+j] = e / sum;
  }
  __syncthreads();

  // aggregate: x2[i][h*128+c] = relu(sum_j alpha[i][j]*gl[j][c] + bias)
  {
    const int i = t>>3, c0 = (t&7)*16;
    float4 o0 = make_float4(0.f,0.f,0.f,0.f), o1 = o0, o2 = o0, o3 = o0;
    for (int j=0;j<32;j++){
      const float al = s_lg[i*33+j];
      o0 = fma4(o0, al, *(const float4*)&s_gl[j*132 + c0]);
      o1 = fma4(o1, al, *(const float4*)&s_gl[j*132 + c0 + 4]);
      o2 = fma4(o2, al, *(const float4*)&s_gl[j*132 + c0 + 8]);
      o3 = fma4(o3, al, *(const float4*)&s_gl[j*132 + c0 + 12]);
    }
    const float4 b0 = *(const float4*)&s_b[c0];
    const float4 b1 = *(const float4*)&s_b[c0+4];
    const float4 b2 = *(const float4*)&s_b[c0+8];
    const float4 b3 = *(const float4*)&s_b[c0+12];
    o0 = relu4(make_float4(o0.x+b0.x, o0.y+b0.y, o0.z+b0.z, o0.w+b0.w));
    o1 = relu4(make_float4(o1.x+b1.x, o1.y+b1.y, o1.z+b1.z, o1.w+b1.w));
    o2 = relu4(make_float4(o2.x+b2.x, o2.y+b2.y, o2.z+b2.z, o2.w+b2.w));
    o3 = relu4(make_float4(o3.x+b3.x, o3.y+b3.y, o3.z+b3.z, o3.w+b3.w));
    float* xp = x2 + ((size_t)s*32 + i)*512 + h*128;
    *(float4*)&xp[c0]    = o0;
    *(float4*)&xp[c0+4]  = o1;
    *(float4*)&xp[c0+8]  = o2;
    *(float4*)&xp[c0+12] = o3;
    if (i == ai){
      float* xc = xcat + (size_t)s*1152 + 128 + h*128;
      *(float4*)&xc[c0]    = o0;
      *(float4*)&xc[c0+4]  = o1;
      *(float4*)&xc[c0+8]  = o2;
      *(float4*)&xc[c0+12] = o3;
    }
  }
}

// =============== K5: gr2-tap + attn2 (row aidx only) + dueling heads ===============
__global__ __launch_bounds__(256) void head_kernel(
    const float* __restrict__ gl2,  // [4096][512]
    const float* __restrict__ x2,   // [4096][512]
    const float* __restrict__ wr2,  // [512][512]
    const float* __restrict__ att2, const float* __restrict__ bias2, // [512],[512]
    const float* __restrict__ q_w1, const float* __restrict__ q_b1,
    const float* __restrict__ q_w2, const float* __restrict__ q_b2,
    const float* __restrict__ v_w1, const float* __restrict__ v_b1,
    const float* __restrict__ v_w2, const float* __restrict__ v_b2,
    const unsigned* __restrict__ adjw, const int* __restrict__ aiw,
    const float* __restrict__ xcatg, // [128][1152] (first 640 valid)
    float* __restrict__ out)
{
  __shared__ __align__(16) float s_xr[512];
  __shared__ __align__(16) float s_grt[512];
  __shared__ __align__(16) float s_att[512];
  __shared__ float s_al[4*33];
  __shared__ __align__(16) float s_xcat[1152];
  __shared__ float s_head[512];
  __shared__ float s_red[40];
  const int t = threadIdx.x;
  const int s = blockIdx.x;
  const int ai = aiw[s];
  const unsigned arow = adjw[s*32 + ai];

  if (t < 128){ *(float4*)&s_xr[t*4] = *(const float4*)&x2[((size_t)s*32 + ai)*512 + t*4]; }
  else        { const int u = t-128; *(float4*)&s_att[u*4] = *(const float4*)&att2[u*4]; }
  if (t < 160){ *(float4*)&s_xcat[t*4] = *(const float4*)&xcatg[(size_t)s*1152 + t*4]; }
  __syncthreads();

  // gr2 tap row: s_grt = x2row @ wr2 (cols 2t, 2t+1)
  {
    float ax = 0.f, ay = 0.f;
    for (int k=0;k<512;k+=4){
      const float4 xv = *(const float4*)&s_xr[k];
      #pragma unroll
      for (int kk=0;kk<4;kk++){
        const float2 w = *(const float2*)&wr2[(size_t)(k+kk)*512 + 2*t];
        const float xs = comp4(xv,kk);
        ax += xs*w.x; ay += xs*w.y;
      }
    }
    s_grt[2*t] = ax; s_grt[2*t+1] = ay;
  }
  __syncthreads();

  // attn2 logits + softmax for row ai, per head (wave w = head h)
  {
    const int h = t>>6, lane = t&63;
    const int j = lane>>1, cb = (lane&1)*64;
    const float* glr = gl2 + ((size_t)s*32 + j)*512 + h*128 + cb;
    const float* at = s_att + h*128 + cb;
    const float* gt = s_grt + h*128 + cb;
    float acc = 0.f;
    for (int c=0;c<64;c+=4){
      const float4 g = *(const float4*)&glr[c];
      const float4 a4 = *(const float4*)&at[c];
      const float4 r4 = *(const float4*)&gt[c];
      float e0 = r4.x+g.x; e0 = fmaxf(e0, 0.2f*e0);
      float e1 = r4.y+g.y; e1 = fmaxf(e1, 0.2f*e1);
      float e2 = r4.z+g.z; e2 = fmaxf(e2, 0.2f*e2);
      float e3 = r4.w+g.w; e3 = fmaxf(e3, 0.2f*e3);
      acc += e0*a4.x + e1*a4.y + e2*a4.z + e3*a4.w;
    }
    acc += __shfl_xor(acc, 1, 64);
    const int jj = lane&31;
    const float lg = __shfl(acc, jj*2, 64);
    const bool ok = (arow>>jj)&1u;
    float v = ok ? lg : -3.0e38f;
    #pragma unroll
    for (int d_=16; d_; d_>>=1) v = fmaxf(v, __shfl_xor(v, d_, 32));
    const float e = ok ? __expf(lg - v) : 0.f;
    float sum = e;
    #pragma unroll
    for (int d_=16; d_; d_>>=1) sum += __shfl_xor(sum, d_, 32);
    if (lane < 32) s_al[h*33 + jj] = e / sum;
  }
  __syncthreads();

  // x3[c] = relu(sum_j alpha[h][j]*gl2[j][c] + bias2[c]) -> s_xcat[640+c]
  {
    const int c0 = 2*t, h = t>>6;
    float ox = 0.f, oy = 0.f;
    for (int j=0;j<32;j++){
      const float al = s_al[h*33 + j];
      const float2 g = *(const float2*)&gl2[((size_t)s*32 + j)*512 + c0];
      ox += al*g.x; oy += al*g.y;
    }
    const float2 bv = *(const float2*)&bias2[c0];
    s_xcat[640 + c0]     = fmaxf(ox + bv.x, 0.f);
    s_xcat[640 + c0 + 1] = fmaxf(oy + bv.y, 0.f);
  }
  __syncthreads();

  // dueling heads layer 1
  {
    const float* w1p; const float* b1p; int cbase, off;
    if (t < 128){ w1p = q_w1; b1p = q_b1; cbase = 2*t;        off = 0;   }
    else        { w1p = v_w1; b1p = v_b1; cbase = 2*(t-128);  off = 256; }
    float ax = 0.f, ay = 0.f;
    for (int k=0;k<1152;k+=4){
      const float4 xv = *(const float4*)&s_xcat[k];
      #pragma unroll
      for (int kk=0;kk<4;kk++){
        const float2 wv = *(const float2*)(w1p + (size_t)(k+kk)*256 + cbase);
        const float xs = comp4(xv,kk);
        ax += xs*wv.x; ay += xs*wv.y;
      }
    }
    const float2 bv = *(const float2*)(b1p + cbase);
    s_head[off+cbase]   = fmaxf(ax + bv.x, 0.f);
    s_head[off+cbase+1] = fmaxf(ay + bv.y, 0.f);
  }
  __syncthreads();

  // final
  {
    const float hq = s_head[t];
    const float hv = s_head[256+t];
    float p0 = hq*q_w2[t*5+0];
    float p1 = hq*q_w2[t*5+1];
    float p2 = hq*q_w2[t*5+2];
    float p3 = hq*q_w2[t*5+3];
    float p4 = hq*q_w2[t*5+4];
    float p5 = hv*v_w2[t];
    #pragma unroll
    for (int d_=32; d_; d_>>=1){
      p0 += __shfl_xor(p0, d_, 64);
      p1 += __shfl_xor(p1, d_, 64);
      p2 += __shfl_xor(p2, d_, 64);
      p3 += __shfl_xor(p3, d_, 64);
      p4 += __shfl_xor(p4, d_, 64);
      p5 += __shfl_xor(p5, d_, 64);
    }
    const int w = t>>6, lane = t&63;
    if (lane==0){
      s_red[w*8+0]=p0; s_red[w*8+1]=p1; s_red[w*8+2]=p2;
      s_red[w*8+3]=p3; s_red[w*8+4]=p4; s_red[w*8+5]=p5;
    }
  }
  __syncthreads();
  if (t < 5){
    const float q = s_red[t] + s_red[8+t] + s_red[16+t] + s_red[24+t] + q_b2[t];
    s_red[32+t] = q;
  }
  __syncthreads();
  if (t < 5){
    const float vs = s_red[5] + s_red[13] + s_red[21] + s_red[29] + v_b2[0];
    const float mean = (s_red[32]+s_red[33]+s_red[34]+s_red[35]+s_red[36]) / 5.0f;
    out[s*5+t] = s_red[32+t] - mean + vs;
  }
}

extern "C" void kernel_launch(void* const* d_in, const int* in_sizes, int n_in,
                              void* d_out, int out_size, void* d_ws, size_t ws_size,
                              hipStream_t stream) {
  (void)n_in; (void)out_size; (void)ws_size;
  const float* obs    = (const float*)d_in[0];
  const float* enc_w1 = (const float*)d_in[1];
  const float* enc_b1 = (const float*)d_in[2];
  const float* enc_w2 = (const float*)d_in[3];
  const float* enc_b2 = (const float*)d_in[4];
  const float* wl1    = (const float*)d_in[5];
  const float* wr1    = (const float*)d_in[6];
  const float* att1   = (const float*)d_in[7];
  const float* bias1  = (const float*)d_in[8];
  const float* wl2    = (const float*)d_in[9];
  const float* wr2    = (const float*)d_in[10];
  const float* att2   = (const float*)d_in[11];
  const float* bias2  = (const float*)d_in[12];
  const float* q_w1   = (const float*)d_in[13];
  const float* q_b1   = (const float*)d_in[14];
  const float* q_w2   = (const float*)d_in[15];
  const float* q_b2   = (const float*)d_in[16];
  const float* v_w1   = (const float*)d_in[17];
  const float* v_b1   = (const float*)d_in[18];
  const float* v_w2   = (const float*)d_in[19];
  const float* v_b2   = (const float*)d_in[20];

  // workspace layout (bytes)
  char* ws = (char*)d_ws;
  float*    x_buf  = (float*)   (ws + 0);           // 4096*128*4   = 2,097,152
  float*    xcat   = (float*)   (ws + 2097152);     // 128*1152*4   =   589,824
  unsigned* adjw   = (unsigned*)(ws + 2686976);     // 128*32*4     =    16,384
  int*      aiw    = (int*)     (ws + 2703360);     // 128*4 (+pad) =       512
  float*    gl_buf = (float*)   (ws + 2703872);     // 4096*512*4   = 8,388,608
  float*    gr_buf = (float*)   (ws + 11092480);    // 4096*512*4   = 8,388,608
  // total 19,481,088 B

  const int bs = in_sizes[0] / 577;   // 128

  enc_kernel<<<bs, 256, 0, stream>>>(obs, enc_w1, enc_b1, enc_w2, enc_b2,
                                     x_buf, xcat, adjw, aiw);

  // proj1: [gl1|gr1] = x @ [wl1|wr1]   (M=4096, K=128, N=512+512)
  gemm_kernel<128><<<64*8, 256, 0, stream>>>(x_buf, wl1, wr1, gl_buf, gr_buf, 8, 4);

  // attn1: x2 (into gr_buf) + x2 tap
  attn1_kernel<<<bs*4, 256, 0, stream>>>(gl_buf, gr_buf, att1, bias1, adjw, aiw,
                                         gr_buf /*x2 aliases gr*/, xcat);

  // proj2: gl2 = x2 @ wl2   (M=4096, K=512, N=512) -> overwrite gl_buf
  gemm_kernel<512><<<64*4, 256, 0, stream>>>(gr_buf, wl2, wl2, gl_buf, gl_buf, 4, 4);

  // gr2-tap + attn2(row ai) + heads
  head_kernel<<<bs, 256, 0, stream>>>(gl_buf, gr_buf, wr2, att2, bias2,
                                      q_w1, q_b1, q_w2, q_b2,
                                      v_w1, v_b1, v_w2, v_b2,
                                      adjw, aiw, xcat, (float*)d_out);
}

// Round 5
// 271.352 us; speedup vs baseline: 1.3923x; 1.0691x over previous
//
#include <hip/hip_runtime.h>
#include <hip/hip_bf16.h>

typedef unsigned int uint_t;

__device__ __forceinline__ float4 fma4(float4 a, float s, float4 w){
  a.x += s*w.x; a.y += s*w.y; a.z += s*w.z; a.w += s*w.w; return a;
}
__device__ __forceinline__ float4 relu4(float4 a){
  return make_float4(fmaxf(a.x,0.f),fmaxf(a.y,0.f),fmaxf(a.z,0.f),fmaxf(a.w,0.f));
}
__device__ __forceinline__ float comp4(float4 v, int k){
  return k==0? v.x : k==1? v.y : k==2? v.z : v.w;
}

// =============== K1: encoder + adjacency + x1 tap ===============
__global__ __launch_bounds__(256) void enc_kernel(
    const float* __restrict__ obs,
    const float* __restrict__ enc_w1, const float* __restrict__ enc_b1,
    const float* __restrict__ enc_w2, const float* __restrict__ enc_b2,
    float* __restrict__ xg,      // [4096][128]
    float* __restrict__ xcat,    // [128][1152]
    unsigned* __restrict__ adjw, int* __restrict__ aiw)
{
  __shared__ float s_pos[64];
  __shared__ float s_feats[512];
  __shared__ __align__(16) float s_h[32*132];
  __shared__ int s_ai;
  const int t = threadIdx.x, s = blockIdx.x;
  const float* ob = obs + s*577;

  if (t < 64) s_pos[t] = ob[(t>>1)*18 + (t&1)];
  for (int e=t; e<512; e+=256){ const int i=e>>4, f=e&15; s_feats[e] = ob[i*18+2+f]; }
  if (t==0){
    float a = ob[576];
    a = fminf(fmaxf(a, 0.f), 31.f);
    const int ai = (int)a;
    s_ai = ai; aiw[s] = ai;
  }
  __syncthreads();

  if (t < 32){
    const float px = s_pos[2*t], py = s_pos[2*t+1];
    const float R2 = 0.09f;
    unsigned m = 0u;
    for (int j=0;j<32;j++){
      const float dx = __fsub_rn(px, s_pos[2*j]), dy = __fsub_rn(py, s_pos[2*j+1]);
      const float d2 = __fadd_rn(__fmul_rn(dx,dx), __fmul_rn(dy,dy));
      if (d2 <= R2 || j==t) m |= (1u<<j);
    }
    adjw[s*32+t] = m;
  }

  // enc1: h = relu(feats @ enc_w1 + b1) -> s_h
  {
    const int i = t>>3, c0 = (t&7)*16;
    float4 a0 = *(const float4*)(enc_b1+c0);
    float4 a1 = *(const float4*)(enc_b1+c0+4);
    float4 a2 = *(const float4*)(enc_b1+c0+8);
    float4 a3 = *(const float4*)(enc_b1+c0+12);
    for (int f=0; f<16; f++){
      const float xs = s_feats[i*16+f];
      const float* p = enc_w1 + f*128 + c0;
      a0 = fma4(a0, xs, *(const float4*)(p));
      a1 = fma4(a1, xs, *(const float4*)(p+4));
      a2 = fma4(a2, xs, *(const float4*)(p+8));
      a3 = fma4(a3, xs, *(const float4*)(p+12));
    }
    *(float4*)&s_h[i*132+c0]    = relu4(a0);
    *(float4*)&s_h[i*132+c0+4]  = relu4(a1);
    *(float4*)&s_h[i*132+c0+8]  = relu4(a2);
    *(float4*)&s_h[i*132+c0+12] = relu4(a3);
  }
  __syncthreads();

  // enc2: x = relu(h @ enc_w2 + b2) -> global xg + tap
  {
    const int i = t>>3, c0 = (t&7)*16;
    float4 a0 = *(const float4*)(enc_b2+c0);
    float4 a1 = *(const float4*)(enc_b2+c0+4);
    float4 a2 = *(const float4*)(enc_b2+c0+8);
    float4 a3 = *(const float4*)(enc_b2+c0+12);
    for (int k=0;k<128;k+=4){
      const float4 hv = *(const float4*)&s_h[i*132+k];
      #pragma unroll
      for (int kk=0;kk<4;kk++){
        const float* p = enc_w2 + (k+kk)*128 + c0;
        const float xs = comp4(hv,kk);
        a0 = fma4(a0, xs, *(const float4*)(p));
        a1 = fma4(a1, xs, *(const float4*)(p+4));
        a2 = fma4(a2, xs, *(const float4*)(p+8));
        a3 = fma4(a3, xs, *(const float4*)(p+12));
      }
    }
    a0 = relu4(a0); a1 = relu4(a1); a2 = relu4(a2); a3 = relu4(a3);
    float* xp = xg + ((size_t)s*32 + i)*128;
    *(float4*)&xp[c0]    = a0;
    *(float4*)&xp[c0+4]  = a1;
    *(float4*)&xp[c0+8]  = a2;
    *(float4*)&xp[c0+12] = a3;
    if (i == s_ai){
      float* xc = xcat + (size_t)s*1152;
      *(float4*)&xc[c0]    = a0;
      *(float4*)&xc[c0+4]  = a1;
      *(float4*)&xc[c0+8]  = a2;
      *(float4*)&xc[c0+12] = a3;
    }
  }
}

// =============== K2/K4: tiled GEMM  C[4096xN] = A[4096xK] @ B[Kx512] ===============
// 32 rows x 128 cols per block, 256 threads, 4x4 per thread, BK=32.
// proj1: 1024 blocks (4/CU), proj2: 512 blocks (2/CU) -> latency hiding.
template<int KDIM>
__global__ __launch_bounds__(256) void gemm_kernel(
    const float* __restrict__ A,
    const float* __restrict__ B0, const float* __restrict__ B1,
    float* __restrict__ C0, float* __restrict__ C1,
    int nct, int ctsplit)
{
  __shared__ __align__(16) float As[32*36];    //  4608 B
  __shared__ __align__(16) float Bs[32*132];   // 16896 B
  const int t = threadIdx.x;
  const int bid = blockIdx.x;
  const int rt = bid / nct, ct = bid % nct;
  const float* B; float* C; int cb;
  if (ct < ctsplit){ B = B0; C = C0; cb = ct*128; }
  else             { B = B1; C = C1; cb = (ct-ctsplit)*128; }
  const int rbase = rt*32;
  const int r0 = (t>>5)*4;       // 0..28 step 4
  const int c0 = (t&31)*4;       // 0..124

  float4 acc[4];
  #pragma unroll
  for (int r=0;r<4;r++) acc[r] = make_float4(0.f,0.f,0.f,0.f);

  const int a_row = t>>3, a_kq = t&7;   // 1 float4/thread for As

  for (int k0 = 0; k0 < KDIM; k0 += 32){
    float4 a_st = *(const float4*)&A[(size_t)(rbase+a_row)*KDIM + k0 + a_kq*4];
    float4 b_st[4];
    #pragma unroll
    for (int i=0;i<4;i++){
      const int e = t + i*256, kk = e>>5, c4 = e&31;
      b_st[i] = *(const float4*)&B[(size_t)(k0+kk)*512 + cb + c4*4];
    }
    __syncthreads();
    *(float4*)&As[a_row*36 + a_kq*4] = a_st;
    #pragma unroll
    for (int i=0;i<4;i++){
      const int e = t + i*256, kk = e>>5, c4 = e&31;
      *(float4*)&Bs[kk*132 + c4*4] = b_st[i];
    }
    __syncthreads();
    #pragma unroll
    for (int kk4=0; kk4<8; kk4++){
      float4 bv[4];
      #pragma unroll
      for (int kk=0;kk<4;kk++) bv[kk] = *(const float4*)&Bs[(kk4*4+kk)*132 + c0];
      #pragma unroll
      for (int r=0;r<4;r++){
        const float4 av = *(const float4*)&As[(r0+r)*36 + kk4*4];
        acc[r] = fma4(acc[r], av.x, bv[0]);
        acc[r] = fma4(acc[r], av.y, bv[1]);
        acc[r] = fma4(acc[r], av.z, bv[2]);
        acc[r] = fma4(acc[r], av.w, bv[3]);
      }
    }
  }
  #pragma unroll
  for (int r=0;r<4;r++){
    *(float4*)&C[(size_t)(rbase + r0 + r)*512 + cb + c0] = acc[r];
  }
}

// =============== K3: GAT layer-1 attention, one block per (sample, head) ===============
__global__ __launch_bounds__(256) void attn1_kernel(
    const float* __restrict__ gl, const float* __restrict__ gr, // [4096][512]
    const float* __restrict__ att, const float* __restrict__ bias, // [4][128], [512]
    const unsigned* __restrict__ adjw, const int* __restrict__ aiw,
    float* __restrict__ x2,   // [4096][512] (aliases gr buffer; safe: slice h only touched by block (s,h))
    float* __restrict__ xcat) // [128][1152]
{
  __shared__ __align__(16) float s_gl[32*132];
  __shared__ __align__(16) float s_gr[32*132];
  __shared__ __align__(16) float s_att[128];
  __shared__ __align__(16) float s_b[128];
  __shared__ float s_lg[32*33];
  __shared__ unsigned s_adj[32];
  const int t = threadIdx.x;
  const int s = blockIdx.x >> 2, h = blockIdx.x & 3;
  const float* glp = gl + (size_t)s*32*512 + h*128;
  const float* grp = gr + (size_t)s*32*512 + h*128;

  {
    const int i = t>>3, c0 = (t&7)*16;
    #pragma unroll
    for (int q=0;q<4;q++){
      *(float4*)&s_gl[i*132 + c0 + q*4] = *(const float4*)&glp[(size_t)i*512 + c0 + q*4];
      *(float4*)&s_gr[i*132 + c0 + q*4] = *(const float4*)&grp[(size_t)i*512 + c0 + q*4];
    }
  }
  if (t < 128){ s_att[t] = att[h*128 + t]; s_b[t] = bias[h*128 + t]; }
  if (t >= 224) s_adj[t-224] = adjw[s*32 + (t-224)];
  const int ai = aiw[s];
  __syncthreads();

  // logits[i][j] = att_h . lrelu(gr[i] + gl[j])
  {
    const int i = t>>3, jb = t&7;
    float acc[4] = {0.f,0.f,0.f,0.f};
    for (int c=0;c<128;c+=4){
      const float4 g = *(const float4*)&s_gr[i*132+c];
      const float4 a = *(const float4*)&s_att[c];
      #pragma unroll
      for (int m=0;m<4;m++){
        const float4 gj = *(const float4*)&s_gl[(jb+8*m)*132 + c];
        float ex = g.x+gj.x; ex = fmaxf(ex, 0.2f*ex);
        float ey = g.y+gj.y; ey = fmaxf(ey, 0.2f*ey);
        float ez = g.z+gj.z; ez = fmaxf(ez, 0.2f*ez);
        float ew = g.w+gj.w; ew = fmaxf(ew, 0.2f*ew);
        acc[m] += ex*a.x + ey*a.y + ez*a.z + ew*a.w;
      }
    }
    #pragma unroll
    for (int m=0;m<4;m++) s_lg[i*33 + jb + 8*m] = acc[m];
  }
  __syncthreads();

  // masked softmax over j (rows i: 4 rounds of 8)
  for (int rnd=0; rnd<4; rnd++){
    const int i = rnd*8 + (t>>5), j = t&31;
    const float lg = s_lg[i*33+j];
    const bool ok = (s_adj[i]>>j)&1u;
    float v = ok ? lg : -3.0e38f;
    #pragma unroll
    for (int d_=16; d_; d_>>=1) v = fmaxf(v, __shfl_xor(v, d_, 32));
    const float e = ok ? __expf(lg - v) : 0.f;
    float sum = e;
    #pragma unroll
    for (int d_=16; d_; d_>>=1) sum += __shfl_xor(sum, d_, 32);
    s_lg[i*33+j] = e / sum;
  }
  __syncthreads();

  // aggregate: x2[i][h*128+c] = relu(sum_j alpha[i][j]*gl[j][c] + bias)
  {
    const int i = t>>3, c0 = (t&7)*16;
    float4 o0 = make_float4(0.f,0.f,0.f,0.f), o1 = o0, o2 = o0, o3 = o0;
    for (int j=0;j<32;j++){
      const float al = s_lg[i*33+j];
      o0 = fma4(o0, al, *(const float4*)&s_gl[j*132 + c0]);
      o1 = fma4(o1, al, *(const float4*)&s_gl[j*132 + c0 + 4]);
      o2 = fma4(o2, al, *(const float4*)&s_gl[j*132 + c0 + 8]);
      o3 = fma4(o3, al, *(const float4*)&s_gl[j*132 + c0 + 12]);
    }
    const float4 b0 = *(const float4*)&s_b[c0];
    const float4 b1 = *(const float4*)&s_b[c0+4];
    const float4 b2 = *(const float4*)&s_b[c0+8];
    const float4 b3 = *(const float4*)&s_b[c0+12];
    o0 = relu4(make_float4(o0.x+b0.x, o0.y+b0.y, o0.z+b0.z, o0.w+b0.w));
    o1 = relu4(make_float4(o1.x+b1.x, o1.y+b1.y, o1.z+b1.z, o1.w+b1.w));
    o2 = relu4(make_float4(o2.x+b2.x, o2.y+b2.y, o2.z+b2.z, o2.w+b2.w));
    o3 = relu4(make_float4(o3.x+b3.x, o3.y+b3.y, o3.z+b3.z, o3.w+b3.w));
    float* xp = x2 + ((size_t)s*32 + i)*512 + h*128;
    *(float4*)&xp[c0]    = o0;
    *(float4*)&xp[c0+4]  = o1;
    *(float4*)&xp[c0+8]  = o2;
    *(float4*)&xp[c0+12] = o3;
    if (i == ai){
      float* xc = xcat + (size_t)s*1152 + 128 + h*128;
      *(float4*)&xc[c0]    = o0;
      *(float4*)&xc[c0+4]  = o1;
      *(float4*)&xc[c0+8]  = o2;
      *(float4*)&xc[c0+12] = o3;
    }
  }
}

// =============== K5: gr2-tap + attn2 (row aidx only) + dueling heads ===============
__global__ __launch_bounds__(256) void head_kernel(
    const float* __restrict__ gl2,  // [4096][512]
    const float* __restrict__ x2,   // [4096][512]
    const float* __restrict__ wr2,  // [512][512]
    const float* __restrict__ att2, const float* __restrict__ bias2, // [512],[512]
    const float* __restrict__ q_w1, const float* __restrict__ q_b1,
    const float* __restrict__ q_w2, const float* __restrict__ q_b2,
    const float* __restrict__ v_w1, const float* __restrict__ v_b1,
    const float* __restrict__ v_w2, const float* __restrict__ v_b2,
    const unsigned* __restrict__ adjw, const int* __restrict__ aiw,
    const float* __restrict__ xcatg, // [128][1152] (first 640 valid)
    float* __restrict__ out)
{
  __shared__ __align__(16) float s_gl2[32*516];  // 66048 B: staged gl2 slice
  __shared__ __align__(16) float s_xr[512];
  __shared__ __align__(16) float s_grt[512];
  __shared__ __align__(16) float s_att[512];
  __shared__ float s_al[4*33];
  __shared__ __align__(16) float s_xcat[1152];
  __shared__ float s_head[512];
  __shared__ float s_red[40];
  const int t = threadIdx.x;
  const int s = blockIdx.x;
  const int ai = aiw[s];
  const unsigned arow = adjw[s*32 + ai];

  // stage gl2 slice (32x512) into LDS, coalesced
  {
    const float* g0 = gl2 + (size_t)s*32*512;
    #pragma unroll
    for (int i=0;i<16;i++){
      const int e = t + i*256, row = e>>7, c4 = e&127;
      *(float4*)&s_gl2[row*516 + c4*4] = *(const float4*)&g0[(size_t)row*512 + c4*4];
    }
  }
  if (t < 128){ *(float4*)&s_xr[t*4] = *(const float4*)&x2[((size_t)s*32 + ai)*512 + t*4]; }
  else        { const int u = t-128; *(float4*)&s_att[u*4] = *(const float4*)&att2[u*4]; }
  if (t < 160){ *(float4*)&s_xcat[t*4] = *(const float4*)&xcatg[(size_t)s*1152 + t*4]; }
  __syncthreads();

  // gr2 tap row: s_grt = x2row @ wr2 (cols 2t, 2t+1)
  {
    float ax = 0.f, ay = 0.f;
    for (int k=0;k<512;k+=4){
      const float4 xv = *(const float4*)&s_xr[k];
      #pragma unroll
      for (int kk=0;kk<4;kk++){
        const float2 w = *(const float2*)&wr2[(size_t)(k+kk)*512 + 2*t];
        const float xs = comp4(xv,kk);
        ax += xs*w.x; ay += xs*w.y;
      }
    }
    s_grt[2*t] = ax; s_grt[2*t+1] = ay;
  }
  __syncthreads();

  // attn2 logits + softmax for row ai, per head (wave w = head h)
  {
    const int h = t>>6, lane = t&63;
    const int j = lane>>1, cb = (lane&1)*64;
    const float* glr = s_gl2 + j*516 + h*128 + cb;
    const float* at = s_att + h*128 + cb;
    const float* gt = s_grt + h*128 + cb;
    float acc = 0.f;
    for (int c=0;c<64;c+=4){
      const float4 g = *(const float4*)&glr[c];
      const float4 a4 = *(const float4*)&at[c];
      const float4 r4 = *(const float4*)&gt[c];
      float e0 = r4.x+g.x; e0 = fmaxf(e0, 0.2f*e0);
      float e1 = r4.y+g.y; e1 = fmaxf(e1, 0.2f*e1);
      float e2 = r4.z+g.z; e2 = fmaxf(e2, 0.2f*e2);
      float e3 = r4.w+g.w; e3 = fmaxf(e3, 0.2f*e3);
      acc += e0*a4.x + e1*a4.y + e2*a4.z + e3*a4.w;
    }
    acc += __shfl_xor(acc, 1, 64);
    const int jj = lane&31;
    const float lg = __shfl(acc, jj*2, 64);
    const bool ok = (arow>>jj)&1u;
    float v = ok ? lg : -3.0e38f;
    #pragma unroll
    for (int d_=16; d_; d_>>=1) v = fmaxf(v, __shfl_xor(v, d_, 32));
    const float e = ok ? __expf(lg - v) : 0.f;
    float sum = e;
    #pragma unroll
    for (int d_=16; d_; d_>>=1) sum += __shfl_xor(sum, d_, 32);
    if (lane < 32) s_al[h*33 + jj] = e / sum;
  }
  __syncthreads();

  // x3[c] = relu(sum_j alpha[h][j]*gl2[j][c] + bias2[c]) -> s_xcat[640+c]
  {
    const int c0 = 2*t, h = t>>6;
    float ox = 0.f, oy = 0.f;
    for (int j=0;j<32;j++){
      const float al = s_al[h*33 + j];
      const float2 g = *(const float2*)&s_gl2[j*516 + c0];
      ox += al*g.x; oy += al*g.y;
    }
    const float2 bv = *(const float2*)&bias2[c0];
    s_xcat[640 + c0]     = fmaxf(ox + bv.x, 0.f);
    s_xcat[640 + c0 + 1] = fmaxf(oy + bv.y, 0.f);
  }
  __syncthreads();

  // dueling heads layer 1
  {
    const float* w1p; const float* b1p; int cbase, off;
    if (t < 128){ w1p = q_w1; b1p = q_b1; cbase = 2*t;        off = 0;   }
    else        { w1p = v_w1; b1p = v_b1; cbase = 2*(t-128);  off = 256; }
    float ax = 0.f, ay = 0.f;
    for (int k=0;k<1152;k+=4){
      const float4 xv = *(const float4*)&s_xcat[k];
      #pragma unroll
      for (int kk=0;kk<4;kk++){
        const float2 wv = *(const float2*)(w1p + (size_t)(k+kk)*256 + cbase);
        const float xs = comp4(xv,kk);
        ax += xs*wv.x; ay += xs*wv.y;
      }
    }
    const float2 bv = *(const float2*)(b1p + cbase);
    s_head[off+cbase]   = fmaxf(ax + bv.x, 0.f);
    s_head[off+cbase+1] = fmaxf(ay + bv.y, 0.f);
  }
  __syncthreads();

  // final
  {
    const float hq = s_head[t];
    const float hv = s_head[256+t];
    float p0 = hq*q_w2[t*5+0];
    float p1 = hq*q_w2[t*5+1];
    float p2 = hq*q_w2[t*5+2];
    float p3 = hq*q_w2[t*5+3];
    float p4 = hq*q_w2[t*5+4];
    float p5 = hv*v_w2[t];
    #pragma unroll
    for (int d_=32; d_; d_>>=1){
      p0 += __shfl_xor(p0, d_, 64);
      p1 += __shfl_xor(p1, d_, 64);
      p2 += __shfl_xor(p2, d_, 64);
      p3 += __shfl_xor(p3, d_, 64);
      p4 += __shfl_xor(p4, d_, 64);
      p5 += __shfl_xor(p5, d_, 64);
    }
    const int w = t>>6, lane = t&63;
    if (lane==0){
      s_red[w*8+0]=p0; s_red[w*8+1]=p1; s_red[w*8+2]=p2;
      s_red[w*8+3]=p3; s_red[w*8+4]=p4; s_red[w*8+5]=p5;
    }
  }
  __syncthreads();
  if (t < 5){
    const float q = s_red[t] + s_red[8+t] + s_red[16+t] + s_red[24+t] + q_b2[t];
    s_red[32+t] = q;
  }
  __syncthreads();
  if (t < 5){
    const float vs = s_red[5] + s_red[13] + s_red[21] + s_red[29] + v_b2[0];
    const float mean = (s_red[32]+s_red[33]+s_red[34]+s_red[35]+s_red[36]) / 5.0f;
    out[s*5+t] = s_red[32+t] - mean + vs;
  }
}

extern "C" void kernel_launch(void* const* d_in, const int* in_sizes, int n_in,
                              void* d_out, int out_size, void* d_ws, size_t ws_size,
                              hipStream_t stream) {
  (void)n_in; (void)out_size; (void)ws_size;
  const float* obs    = (const float*)d_in[0];
  const float* enc_w1 = (const float*)d_in[1];
  const float* enc_b1 = (const float*)d_in[2];
  const float* enc_w2 = (const float*)d_in[3];
  const float* enc_b2 = (const float*)d_in[4];
  const float* wl1    = (const float*)d_in[5];
  const float* wr1    = (const float*)d_in[6];
  const float* att1   = (const float*)d_in[7];
  const float* bias1  = (const float*)d_in[8];
  const float* wl2    = (const float*)d_in[9];
  const float* wr2    = (const float*)d_in[10];
  const float* att2   = (const float*)d_in[11];
  const float* bias2  = (const float*)d_in[12];
  const float* q_w1   = (const float*)d_in[13];
  const float* q_b1   = (const float*)d_in[14];
  const float* q_w2   = (const float*)d_in[15];
  const float* q_b2   = (const float*)d_in[16];
  const float* v_w1   = (const float*)d_in[17];
  const float* v_b1   = (const float*)d_in[18];
  const float* v_w2   = (const float*)d_in[19];
  const float* v_b2   = (const float*)d_in[20];

  // workspace layout (bytes)
  char* ws = (char*)d_ws;
  float*    x_buf  = (float*)   (ws + 0);           // 4096*128*4   = 2,097,152
  float*    xcat   = (float*)   (ws + 2097152);     // 128*1152*4   =   589,824
  unsigned* adjw   = (unsigned*)(ws + 2686976);     // 128*32*4     =    16,384
  int*      aiw    = (int*)     (ws + 2703360);     // 128*4 (+pad) =       512
  float*    gl_buf = (float*)   (ws + 2703872);     // 4096*512*4   = 8,388,608
  float*    gr_buf = (float*)   (ws + 11092480);    // 4096*512*4   = 8,388,608
  // total 19,481,088 B

  const int bs = in_sizes[0] / 577;   // 128

  enc_kernel<<<bs, 256, 0, stream>>>(obs, enc_w1, enc_b1, enc_w2, enc_b2,
                                     x_buf, xcat, adjw, aiw);

  // proj1: [gl1|gr1] = x @ [wl1|wr1]   (M=4096, K=128, N=512+512) — 128 rt x 8 ct
  gemm_kernel<128><<<128*8, 256, 0, stream>>>(x_buf, wl1, wr1, gl_buf, gr_buf, 8, 4);

  // attn1: x2 (into gr_buf) + x2 tap
  attn1_kernel<<<bs*4, 256, 0, stream>>>(gl_buf, gr_buf, att1, bias1, adjw, aiw,
                                         gr_buf /*x2 aliases gr*/, xcat);

  // proj2: gl2 = x2 @ wl2   (M=4096, K=512, N=512) — 128 rt x 4 ct
  gemm_kernel<512><<<128*4, 256, 0, stream>>>(gr_buf, wl2, wl2, gl_buf, gl_buf, 4, 4);

  // gr2-tap + attn2(row ai) + heads
  head_kernel<<<bs, 256, 0, stream>>>(gl_buf, gr_buf, wr2, att2, bias2,
                                      q_w1, q_b1, q_w2, q_b2,
                                      v_w1, v_b1, v_w2, v_b2,
                                      adjw, aiw, xcat, (float*)d_out);
}